// Round 1
// baseline (606.823 us; speedup 1.0000x reference)
//
#include <hip/hip_runtime.h>
#include <hip/hip_bf16.h>

typedef __attribute__((ext_vector_type(8))) short bf16x8;
typedef __attribute__((ext_vector_type(4))) float f32x4;

#define MFMA16(a, b, c) __builtin_amdgcn_mfma_f32_16x16x32_bf16((a), (b), (c), 0, 0, 0)

__device__ __forceinline__ short f2b(float f) {
  unsigned u = __builtin_bit_cast(unsigned, f);
  u += 0x7FFFu + ((u >> 16) & 1u);
  return (short)(u >> 16);
}

// ---------------------------------------------------------------- convert
__global__ __launch_bounds__(256) void cvt_bf16(const float* __restrict__ s,
                                                short* __restrict__ d, int n8) {
  int i = blockIdx.x * 256 + threadIdx.x;
  if (i >= n8) return;
  const float4* sp = (const float4*)s;
  float4 a = sp[2 * i], b = sp[2 * i + 1];
  bf16x8 o;
  o[0] = f2b(a.x); o[1] = f2b(a.y); o[2] = f2b(a.z); o[3] = f2b(a.w);
  o[4] = f2b(b.x); o[5] = f2b(b.y); o[6] = f2b(b.z); o[7] = f2b(b.w);
  *(bf16x8*)(d + (long)i * 8) = o;
}

// ---------------------------------------------------------------- GEMM
// C = A(MxK) @ BT(NxK)^T, bf16 in, f32 accum.
// MODE 0: bf16 out head-major  [B,H,S,64]   (m = b*2048+s, n = h*64+dh)
// MODE 1: bf16 out head-transposed [B,H,64,S]
// MODE 2: f32  out row-major [M][N]
template <int MODE>
__global__ __launch_bounds__(256) void gemm_bt(const short* __restrict__ A,
                                               const short* __restrict__ BT,
                                               void* __restrict__ Cout,
                                               int M, int N, int K) {
  __shared__ __align__(16) short As[128 * 64];
  __shared__ __align__(16) short Bs[128 * 64];
  const int t = threadIdx.x;
  const int l = t & 63, w = t >> 6;
  const int grp = l >> 4, li = l & 15;
  const int nbn = N >> 7;
  const int bm = (int)blockIdx.x / nbn, bn = (int)blockIdx.x % nbn;
  const int m0 = bm << 7, n0 = bn << 7;
  const int wm = (w >> 1) << 6, wn = (w & 1) << 6;
  const int srow = t >> 3, scol = (t & 7) << 3;
  f32x4 acc[4][4] = {};
  for (int kt = 0; kt < K; kt += 64) {
#pragma unroll
    for (int i = 0; i < 4; ++i) {
      const short* ga = A + (long)(m0 + i * 32 + srow) * K + kt + scol;
      __builtin_amdgcn_global_load_lds(
          (const __attribute__((address_space(1))) void*)ga,
          (__attribute__((address_space(3))) void*)&As[i * 2048 + t * 8], 16, 0, 0);
    }
#pragma unroll
    for (int i = 0; i < 4; ++i) {
      const short* gb = BT + (long)(n0 + i * 32 + srow) * K + kt + scol;
      __builtin_amdgcn_global_load_lds(
          (const __attribute__((address_space(1))) void*)gb,
          (__attribute__((address_space(3))) void*)&Bs[i * 2048 + t * 8], 16, 0, 0);
    }
    __syncthreads();
#pragma unroll
    for (int kk = 0; kk < 64; kk += 32) {
      bf16x8 af[4], bfr[4];
#pragma unroll
      for (int mi = 0; mi < 4; ++mi)
        af[mi] = *(const bf16x8*)&As[(wm + mi * 16 + li) * 64 + kk + grp * 8];
#pragma unroll
      for (int ni = 0; ni < 4; ++ni)
        bfr[ni] = *(const bf16x8*)&Bs[(wn + ni * 16 + li) * 64 + kk + grp * 8];
#pragma unroll
      for (int mi = 0; mi < 4; ++mi)
#pragma unroll
        for (int ni = 0; ni < 4; ++ni)
          acc[mi][ni] = MFMA16(af[mi], bfr[ni], acc[mi][ni]);
    }
    __syncthreads();
  }
#pragma unroll
  for (int mi = 0; mi < 4; ++mi) {
#pragma unroll
    for (int ni = 0; ni < 4; ++ni) {
      f32x4 v = acc[mi][ni];
      int n = n0 + wn + ni * 16 + li;
#pragma unroll
      for (int r = 0; r < 4; ++r) {
        int m = m0 + wm + mi * 16 + grp * 4 + r;
        if (MODE == 2) {
          ((float*)Cout)[(long)m * N + n] = v[r];
        } else {
          int b = m >> 11, sq = m & 2047;
          int h = n >> 6, dh = n & 63;
          if (MODE == 0)
            ((short*)Cout)[(((long)(b * 16 + h) * 2048 + sq) << 6) + dh] = f2b(v[r]);
          else
            ((short*)Cout)[(((long)(b * 16 + h) * 64 + dh) << 11) + sq] = f2b(v[r]);
        }
      }
    }
  }
}

// ---------------------------------------------------------------- attention
// Qh,Kh: [B,H,S,64] bf16; Vt: [B,H,64,S] bf16; Xb out: [B,S,D] bf16.
// Block = 4 waves; wave handles 16 q rows; 64-key tiles; causal.
__global__ __launch_bounds__(256) void attn_fwd(const short* __restrict__ Qh,
                                                const short* __restrict__ Kh,
                                                const short* __restrict__ Vt,
                                                short* __restrict__ Xb) {
  __shared__ __align__(16) short Pl[4][1024];
  const int qt = blockIdx.x;   // 0..31
  const int bh = blockIdx.y;   // 0..63
  const int t = threadIdx.x, l = t & 63, w = t >> 6;
  const int grp = l >> 4, li = l & 15;
  const int q0 = qt * 64 + w * 16;
  const short* Qp = Qh + (long)bh * 131072 + (long)q0 * 64;
  const short* Kp = Kh + (long)bh * 131072;
  const short* Vp = Vt + (long)bh * 131072;
  bf16x8 aQ0 = *(const bf16x8*)(Qp + li * 64 + grp * 8);
  bf16x8 aQ1 = *(const bf16x8*)(Qp + li * 64 + 32 + grp * 8);
  f32x4 o[4] = {};
  float mr[4] = {-1e30f, -1e30f, -1e30f, -1e30f};
  float ls[4] = {};
  const int nt = qt + 1;
  for (int kt = 0; kt < nt; ++kt) {
    const short* Kt = Kp + kt * 4096;
    f32x4 sc[4];
#pragma unroll
    for (int kb = 0; kb < 4; ++kb) {
      bf16x8 b0 = *(const bf16x8*)(Kt + (kb * 16 + li) * 64 + grp * 8);
      bf16x8 b1 = *(const bf16x8*)(Kt + (kb * 16 + li) * 64 + 32 + grp * 8);
      f32x4 z = {};
      z = MFMA16(aQ0, b0, z);
      z = MFMA16(aQ1, b1, z);
      sc[kb] = z;
    }
    const bool diag = (kt == qt);
    float tmax[4] = {-1e30f, -1e30f, -1e30f, -1e30f};
#pragma unroll
    for (int kb = 0; kb < 4; ++kb)
#pragma unroll
      for (int r = 0; r < 4; ++r) {
        float v = sc[kb][r] * 0.125f;
        if (diag && (kb * 16 + li > w * 16 + grp * 4 + r)) v = -1e30f;
        sc[kb][r] = v;
        tmax[r] = fmaxf(tmax[r], v);
      }
#pragma unroll
    for (int dd = 1; dd < 16; dd <<= 1)
#pragma unroll
      for (int r = 0; r < 4; ++r)
        tmax[r] = fmaxf(tmax[r], __shfl_xor(tmax[r], dd));
    float alpha[4];
#pragma unroll
    for (int r = 0; r < 4; ++r) {
      float mn = fmaxf(mr[r], tmax[r]);
      alpha[r] = __expf(mr[r] - mn);
      mr[r] = mn;
    }
    float tsum[4] = {};
#pragma unroll
    for (int kb = 0; kb < 4; ++kb)
#pragma unroll
      for (int r = 0; r < 4; ++r) {
        float p = (sc[kb][r] < -1e29f) ? 0.f : __expf(sc[kb][r] - mr[r]);
        tsum[r] += p;
        Pl[w][(grp * 4 + r) * 64 + kb * 16 + li] = f2b(p);
      }
#pragma unroll
    for (int dd = 1; dd < 16; dd <<= 1)
#pragma unroll
      for (int r = 0; r < 4; ++r)
        tsum[r] += __shfl_xor(tsum[r], dd);
#pragma unroll
    for (int r = 0; r < 4; ++r)
      ls[r] = ls[r] * alpha[r] + tsum[r];
#pragma unroll
    for (int d4 = 0; d4 < 4; ++d4)
#pragma unroll
      for (int r = 0; r < 4; ++r)
        o[d4][r] *= alpha[r];
#pragma unroll
    for (int half = 0; half < 2; ++half) {
      bf16x8 aP = *(const bf16x8*)&Pl[w][li * 64 + half * 32 + grp * 8];
#pragma unroll
      for (int d4 = 0; d4 < 4; ++d4) {
        bf16x8 bV = *(const bf16x8*)(Vp + (long)(d4 * 16 + li) * 2048 + kt * 64 + half * 32 + grp * 8);
        o[d4] = MFMA16(aP, bV, o[d4]);
      }
    }
  }
  const int b = bh >> 4, h = bh & 15;
#pragma unroll
  for (int d4 = 0; d4 < 4; ++d4)
#pragma unroll
    for (int r = 0; r < 4; ++r) {
      float v = o[d4][r] / ls[r];
      int sq = q0 + grp * 4 + r;
      Xb[(long)(b * 2048 + sq) * 1024 + h * 64 + d4 * 16 + li] = f2b(v);
    }
}

// ---------------------------------------------------------------- launch
extern "C" void kernel_launch(void* const* d_in, const int* in_sizes, int n_in,
                              void* d_out, int out_size, void* d_ws, size_t ws_size,
                              hipStream_t stream) {
  const float* q  = (const float*)d_in[0];
  const float* k  = (const float*)d_in[1];
  const float* v  = (const float*)d_in[2];
  // d_in[3] = causal tril mask, hardcoded in attn_fwd
  const float* wq = (const float*)d_in[4];
  const float* wk = (const float*)d_in[5];
  const float* wv = (const float*)d_in[6];
  const float* wo = (const float*)d_in[7];

  short* ws = (short*)d_ws;
  const long T = 8388608;  // B*S*D = 4*2048*1024
  short* qb  = ws;
  short* kb  = qb + T;
  short* vb  = kb + T;
  short* Qh  = vb + T;
  short* Kh  = Qh + T;
  short* Vt  = Kh + T;
  short* Xb  = Vt + T;
  short* wqb = Xb + T;
  short* wkb = wqb + 1048576;
  short* wvb = wkb + 1048576;
  short* wob = wvb + 1048576;
  // total ws use: 7*16MiB + 4*2MiB = 120 MiB

  cvt_bf16<<<4096, 256, 0, stream>>>(q, qb, 1048576);
  cvt_bf16<<<4096, 256, 0, stream>>>(k, kb, 1048576);
  cvt_bf16<<<4096, 256, 0, stream>>>(v, vb, 1048576);
  cvt_bf16<<<512, 256, 0, stream>>>(wq, wqb, 131072);
  cvt_bf16<<<512, 256, 0, stream>>>(wk, wkb, 131072);
  cvt_bf16<<<512, 256, 0, stream>>>(wv, wvb, 131072);
  cvt_bf16<<<512, 256, 0, stream>>>(wo, wob, 131072);

  gemm_bt<0><<<512, 256, 0, stream>>>(qb, wqb, (void*)Qh, 8192, 1024, 1024);
  gemm_bt<0><<<512, 256, 0, stream>>>(kb, wkb, (void*)Kh, 8192, 1024, 1024);
  gemm_bt<1><<<512, 256, 0, stream>>>(vb, wvb, (void*)Vt, 8192, 1024, 1024);
  attn_fwd<<<dim3(32, 64), 256, 0, stream>>>(Qh, Kh, Vt, Xb);
  gemm_bt<2><<<512, 256, 0, stream>>>(Xb, wob, d_out, 8192, 1024, 1024);
}

// Round 2
// 275.603 us; speedup vs baseline: 2.2018x; 2.2018x over previous
//
#include <hip/hip_runtime.h>
#include <hip/hip_bf16.h>

typedef __attribute__((ext_vector_type(8))) short bf16x8;
typedef __attribute__((ext_vector_type(4))) float f32x4;

#define MFMA16(a, b, c) __builtin_amdgcn_mfma_f32_16x16x32_bf16((a), (b), (c), 0, 0, 0)

__device__ __forceinline__ short f2b(float f) {
  unsigned u = __builtin_bit_cast(unsigned, f);
  u += 0x7FFFu + ((u >> 16) & 1u);
  return (short)(u >> 16);
}

// ---------------------------------------------------------------- convert
__global__ __launch_bounds__(256) void cvt_bf16(const float* __restrict__ s,
                                                short* __restrict__ d, int n8) {
  int i = blockIdx.x * 256 + threadIdx.x;
  if (i >= n8) return;
  const float4* sp = (const float4*)s;
  float4 a = sp[2 * i], b = sp[2 * i + 1];
  bf16x8 o;
  o[0] = f2b(a.x); o[1] = f2b(a.y); o[2] = f2b(a.z); o[3] = f2b(a.w);
  o[4] = f2b(b.x); o[5] = f2b(b.y); o[6] = f2b(b.z); o[7] = f2b(b.w);
  *(bf16x8*)(d + (long)i * 8) = o;
}

// ---------------------------------------------------------------- GEMM
// C = A(MxK) @ BT(NxK)^T, bf16 in, f32 accum.
// MODE 0: bf16 out head-major  [B,H,S,64]
// MODE 1: bf16 out head-transposed [B,H,64,S]
// MODE 2: f32  out row-major [M][N]
template <int MODE>
__global__ __launch_bounds__(256) void gemm_bt(const short* __restrict__ A,
                                               const short* __restrict__ BT,
                                               void* __restrict__ Cout,
                                               int M, int N, int K) {
  __shared__ __align__(16) short As[128 * 64];
  __shared__ __align__(16) short Bs[128 * 64];
  const int t = threadIdx.x;
  const int l = t & 63, w = t >> 6;
  const int grp = l >> 4, li = l & 15;
  const int nbn = N >> 7;
  const int bm = (int)blockIdx.x / nbn, bn = (int)blockIdx.x % nbn;
  const int m0 = bm << 7, n0 = bn << 7;
  const int wm = (w >> 1) << 6, wn = (w & 1) << 6;
  const int srow = t >> 3, scol = (t & 7) << 3;
  f32x4 acc[4][4] = {};
  for (int kt = 0; kt < K; kt += 64) {
#pragma unroll
    for (int i = 0; i < 4; ++i) {
      const short* ga = A + (long)(m0 + i * 32 + srow) * K + kt + scol;
      __builtin_amdgcn_global_load_lds(
          (const __attribute__((address_space(1))) void*)ga,
          (__attribute__((address_space(3))) void*)&As[i * 2048 + t * 8], 16, 0, 0);
    }
#pragma unroll
    for (int i = 0; i < 4; ++i) {
      const short* gb = BT + (long)(n0 + i * 32 + srow) * K + kt + scol;
      __builtin_amdgcn_global_load_lds(
          (const __attribute__((address_space(1))) void*)gb,
          (__attribute__((address_space(3))) void*)&Bs[i * 2048 + t * 8], 16, 0, 0);
    }
    __syncthreads();
#pragma unroll
    for (int kk = 0; kk < 64; kk += 32) {
      bf16x8 af[4], bfr[4];
#pragma unroll
      for (int mi = 0; mi < 4; ++mi)
        af[mi] = *(const bf16x8*)&As[(wm + mi * 16 + li) * 64 + kk + grp * 8];
#pragma unroll
      for (int ni = 0; ni < 4; ++ni)
        bfr[ni] = *(const bf16x8*)&Bs[(wn + ni * 16 + li) * 64 + kk + grp * 8];
#pragma unroll
      for (int mi = 0; mi < 4; ++mi)
#pragma unroll
        for (int ni = 0; ni < 4; ++ni)
          acc[mi][ni] = MFMA16(af[mi], bfr[ni], acc[mi][ni]);
    }
    __syncthreads();
  }
#pragma unroll
  for (int mi = 0; mi < 4; ++mi) {
#pragma unroll
    for (int ni = 0; ni < 4; ++ni) {
      f32x4 v = acc[mi][ni];
      int n = n0 + wn + ni * 16 + li;
#pragma unroll
      for (int r = 0; r < 4; ++r) {
        int m = m0 + wm + mi * 16 + grp * 4 + r;
        if (MODE == 2) {
          ((float*)Cout)[(long)m * N + n] = v[r];
        } else {
          int b = m >> 11, sq = m & 2047;
          int h = n >> 6, dh = n & 63;
          if (MODE == 0)
            ((short*)Cout)[(((long)(b * 16 + h) * 2048 + sq) << 6) + dh] = f2b(v[r]);
          else
            ((short*)Cout)[(((long)(b * 16 + h) * 64 + dh) << 11) + sq] = f2b(v[r]);
        }
      }
    }
  }
}

// ---------------------------------------------------------------- attention v2
// Qh,Kh: [B,H,S,64] bf16; Vt: [B,H,64,S] bf16; Xb out: [B,S,D] bf16.
// Block = 4 waves, 128 q-rows (32/wave, 2 sets of 16). K/V tiles (64 keys)
// staged to LDS cooperatively, double-buffered, async-split (T14).
__global__ __launch_bounds__(256, 3) void attn_fwd(const short* __restrict__ Qh,
                                                   const short* __restrict__ Kh,
                                                   const short* __restrict__ Vt,
                                                   short* __restrict__ Xb) {
  __shared__ __align__(16) short Ks[2][64][72];
  __shared__ __align__(16) short Vs[2][64][72];
  __shared__ __align__(16) short Ps[4][16][72];
  const int bh = blockIdx.x;               // 0..63
  const int qt = 15 - (int)blockIdx.y;     // heavy blocks dispatch first
  const int t = threadIdx.x, l = t & 63, w = t >> 6;
  const int grp = l >> 4, li = l & 15;
  const int q0w = qt * 128 + w * 32;
  const short* Qp = Qh + (long)bh * 131072;
  const short* Kp = Kh + (long)bh * 131072;
  const short* Vp = Vt + (long)bh * 131072;

  bf16x8 aQ[2][2];
#pragma unroll
  for (int s = 0; s < 2; ++s) {
    const short* qp = Qp + (long)(q0w + s * 16 + li) * 64;
    aQ[s][0] = *(const bf16x8*)(qp + grp * 8);
    aQ[s][1] = *(const bf16x8*)(qp + 32 + grp * 8);
  }

  // staging coords: 256 threads cover 64 rows x 128B in 2 rounds per matrix
  const int r0 = t >> 3, r1 = r0 + 32, sc8 = (t & 7) * 8;
  bf16x8 rk0, rk1, rv0, rv1;
  auto LOADT = [&](int kt) {
    rk0 = *(const bf16x8*)(Kp + (long)(kt * 64 + r0) * 64 + sc8);
    rk1 = *(const bf16x8*)(Kp + (long)(kt * 64 + r1) * 64 + sc8);
    rv0 = *(const bf16x8*)(Vp + (long)r0 * 2048 + kt * 64 + sc8);
    rv1 = *(const bf16x8*)(Vp + (long)r1 * 2048 + kt * 64 + sc8);
  };
  auto WRITET = [&](int buf) {
    *(bf16x8*)&Ks[buf][r0][sc8] = rk0;
    *(bf16x8*)&Ks[buf][r1][sc8] = rk1;
    *(bf16x8*)&Vs[buf][r0][sc8] = rv0;
    *(bf16x8*)&Vs[buf][r1][sc8] = rv1;
  };

  f32x4 o[2][4] = {};
  float mr[2][4], ls[2][4];
#pragma unroll
  for (int s = 0; s < 2; ++s)
#pragma unroll
    for (int r = 0; r < 4; ++r) { mr[s][r] = -1e30f; ls[s][r] = 0.f; }

  const int nts[2] = {(q0w >> 6) + 1, ((q0w + 16) >> 6) + 1};
  const int nt = 2 * qt + 2;

  LOADT(0);
  WRITET(0);
  __syncthreads();

  for (int kt = 0; kt < nt; ++kt) {
    const int buf = kt & 1;
    const bool pre = (kt + 1 < nt);
    if (pre) LOADT(kt + 1);  // issue early; vmcnt waited at WRITET (T14)

#pragma unroll
    for (int s = 0; s < 2; ++s) {
      if (kt < nts[s]) {
        // ---- scores: QK^T
        f32x4 sc[4];
#pragma unroll
        for (int kb = 0; kb < 4; ++kb) {
          bf16x8 b0 = *(const bf16x8*)&Ks[buf][kb * 16 + li][grp * 8];
          bf16x8 b1 = *(const bf16x8*)&Ks[buf][kb * 16 + li][32 + grp * 8];
          f32x4 z = {};
          z = MFMA16(aQ[s][0], b0, z);
          z = MFMA16(aQ[s][1], b1, z);
          sc[kb] = z;
        }
        // ---- scale + causal mask + row max
        const int qrb = q0w + s * 16 + grp * 4;
        float tmax[4] = {-1e30f, -1e30f, -1e30f, -1e30f};
#pragma unroll
        for (int kb = 0; kb < 4; ++kb) {
          const int key = kt * 64 + kb * 16 + li;
#pragma unroll
          for (int r = 0; r < 4; ++r) {
            float v = sc[kb][r] * 0.125f;
            if (key > qrb + r) v = -1e30f;
            sc[kb][r] = v;
            tmax[r] = fmaxf(tmax[r], v);
          }
        }
#pragma unroll
        for (int dd = 1; dd < 16; dd <<= 1)
#pragma unroll
          for (int r = 0; r < 4; ++r)
            tmax[r] = fmaxf(tmax[r], __shfl_xor(tmax[r], dd));
        float alpha[4], mcur[4];
#pragma unroll
        for (int r = 0; r < 4; ++r) {
          float mn = fmaxf(mr[s][r], tmax[r]);
          alpha[r] = __expf(mr[s][r] - mn);
          mr[s][r] = mn;
          mcur[r] = mn;
        }
        // ---- exp + P write + row sum
        float tsum[4] = {0.f, 0.f, 0.f, 0.f};
#pragma unroll
        for (int kb = 0; kb < 4; ++kb)
#pragma unroll
          for (int r = 0; r < 4; ++r) {
            float p = __expf(sc[kb][r] - mcur[r]);
            tsum[r] += p;
            Ps[w][grp * 4 + r][kb * 16 + li] = f2b(p);
          }
#pragma unroll
        for (int dd = 1; dd < 16; dd <<= 1)
#pragma unroll
          for (int r = 0; r < 4; ++r)
            tsum[r] += __shfl_xor(tsum[r], dd);
#pragma unroll
        for (int r = 0; r < 4; ++r)
          ls[s][r] = ls[s][r] * alpha[r] + tsum[r];
#pragma unroll
        for (int d4 = 0; d4 < 4; ++d4)
#pragma unroll
          for (int r = 0; r < 4; ++r)
            o[s][d4][r] *= alpha[r];
        // ---- PV
#pragma unroll
        for (int half = 0; half < 2; ++half) {
          bf16x8 aP = *(const bf16x8*)&Ps[w][li][half * 32 + grp * 8];
#pragma unroll
          for (int d4 = 0; d4 < 4; ++d4) {
            bf16x8 bV = *(const bf16x8*)&Vs[buf][d4 * 16 + li][half * 32 + grp * 8];
            o[s][d4] = MFMA16(aP, bV, o[s][d4]);
          }
        }
      }
    }

    if (pre) WRITET(buf ^ 1);  // vmcnt drain + ds_write to other buffer
    __syncthreads();
  }

  const int b = bh >> 4, h = bh & 15;
#pragma unroll
  for (int s = 0; s < 2; ++s)
#pragma unroll
    for (int d4 = 0; d4 < 4; ++d4)
#pragma unroll
      for (int r = 0; r < 4; ++r) {
        float v = o[s][d4][r] / ls[s][r];
        int sq = q0w + s * 16 + grp * 4 + r;
        Xb[(long)(b * 2048 + sq) * 1024 + h * 64 + d4 * 16 + li] = f2b(v);
      }
}

// ---------------------------------------------------------------- launch
extern "C" void kernel_launch(void* const* d_in, const int* in_sizes, int n_in,
                              void* d_out, int out_size, void* d_ws, size_t ws_size,
                              hipStream_t stream) {
  const float* q  = (const float*)d_in[0];
  const float* k  = (const float*)d_in[1];
  const float* v  = (const float*)d_in[2];
  // d_in[3] = causal tril mask, hardcoded in attn_fwd
  const float* wq = (const float*)d_in[4];
  const float* wk = (const float*)d_in[5];
  const float* wv = (const float*)d_in[6];
  const float* wo = (const float*)d_in[7];

  short* ws = (short*)d_ws;
  const long T = 8388608;  // B*S*D
  short* qb  = ws;
  short* kb  = qb + T;
  short* vb  = kb + T;
  short* Qh  = vb + T;
  short* Kh  = Qh + T;
  short* Vt  = Kh + T;
  short* Xb  = Vt + T;
  short* wqb = Xb + T;
  short* wkb = wqb + 1048576;
  short* wvb = wkb + 1048576;
  short* wob = wvb + 1048576;

  cvt_bf16<<<4096, 256, 0, stream>>>(q, qb, 1048576);
  cvt_bf16<<<4096, 256, 0, stream>>>(k, kb, 1048576);
  cvt_bf16<<<4096, 256, 0, stream>>>(v, vb, 1048576);
  cvt_bf16<<<512, 256, 0, stream>>>(wq, wqb, 131072);
  cvt_bf16<<<512, 256, 0, stream>>>(wk, wkb, 131072);
  cvt_bf16<<<512, 256, 0, stream>>>(wv, wvb, 131072);
  cvt_bf16<<<512, 256, 0, stream>>>(wo, wob, 131072);

  gemm_bt<0><<<512, 256, 0, stream>>>(qb, wqb, (void*)Qh, 8192, 1024, 1024);
  gemm_bt<0><<<512, 256, 0, stream>>>(kb, wkb, (void*)Kh, 8192, 1024, 1024);
  gemm_bt<1><<<512, 256, 0, stream>>>(vb, wvb, (void*)Vt, 8192, 1024, 1024);
  attn_fwd<<<dim3(64, 16), 256, 0, stream>>>(Qh, Kh, Vt, Xb);
  gemm_bt<2><<<512, 256, 0, stream>>>(Xb, wob, d_out, 8192, 1024, 1024);
}

// Round 3
// 240.664 us; speedup vs baseline: 2.5215x; 1.1452x over previous
//
#include <hip/hip_runtime.h>
#include <hip/hip_bf16.h>

typedef __attribute__((ext_vector_type(8))) short bf16x8;
typedef __attribute__((ext_vector_type(4))) float f32x4;
typedef __attribute__((ext_vector_type(16))) float f32x16;

#define MFMA16(a, b, c) __builtin_amdgcn_mfma_f32_16x16x32_bf16((a), (b), (c), 0, 0, 0)
#define MFMA32(a, b, c) __builtin_amdgcn_mfma_f32_32x32x16_bf16((a), (b), (c), 0, 0, 0)

__device__ __forceinline__ short f2b(float f) {
  unsigned u = __builtin_bit_cast(unsigned, f);
  u += 0x7FFFu + ((u >> 16) & 1u);
  return (short)(u >> 16);
}
__device__ __forceinline__ unsigned cvtpk(float lo, float hi) {
  unsigned r;
  asm("v_cvt_pk_bf16_f32 %0, %1, %2" : "=v"(r) : "v"(lo), "v"(hi));
  return r;
}

// ---------------------------------------------------------------- convert
__global__ __launch_bounds__(256) void cvt_bf16(const float* __restrict__ s,
                                                short* __restrict__ d, int n8) {
  int i = blockIdx.x * 256 + threadIdx.x;
  if (i >= n8) return;
  const float4* sp = (const float4*)s;
  float4 a = sp[2 * i], b = sp[2 * i + 1];
  bf16x8 o;
  o[0] = f2b(a.x); o[1] = f2b(a.y); o[2] = f2b(a.z); o[3] = f2b(a.w);
  o[4] = f2b(b.x); o[5] = f2b(b.y); o[6] = f2b(b.z); o[7] = f2b(b.w);
  *(bf16x8*)(d + (long)i * 8) = o;
}

// ---------------------------------------------------------------- GEMM
// C = A(MxK) @ BT(NxK)^T, bf16 in, f32 accum, out scaled by oscale.
// MODE 0: bf16 out head-major [B,H,S,64]; MODE 1: bf16 out [B,H,64,S]; MODE 2: f32 [M][N]
template <int MODE>
__global__ __launch_bounds__(256) void gemm_bt(const short* __restrict__ A,
                                               const short* __restrict__ BT,
                                               void* __restrict__ Cout,
                                               int M, int N, int K, float oscale) {
  __shared__ __align__(16) short As[128 * 64];
  __shared__ __align__(16) short Bs[128 * 64];
  const int t = threadIdx.x;
  const int l = t & 63, w = t >> 6;
  const int grp = l >> 4, li = l & 15;
  const int nbn = N >> 7;
  const int bm = (int)blockIdx.x / nbn, bn = (int)blockIdx.x % nbn;
  const int m0 = bm << 7, n0 = bn << 7;
  const int wm = (w >> 1) << 6, wn = (w & 1) << 6;
  const int srow = t >> 3, scol = (t & 7) << 3;
  f32x4 acc[4][4] = {};
  for (int kt = 0; kt < K; kt += 64) {
#pragma unroll
    for (int i = 0; i < 4; ++i) {
      const short* ga = A + (long)(m0 + i * 32 + srow) * K + kt + scol;
      __builtin_amdgcn_global_load_lds(
          (const __attribute__((address_space(1))) void*)ga,
          (__attribute__((address_space(3))) void*)&As[i * 2048 + t * 8], 16, 0, 0);
    }
#pragma unroll
    for (int i = 0; i < 4; ++i) {
      const short* gb = BT + (long)(n0 + i * 32 + srow) * K + kt + scol;
      __builtin_amdgcn_global_load_lds(
          (const __attribute__((address_space(1))) void*)gb,
          (__attribute__((address_space(3))) void*)&Bs[i * 2048 + t * 8], 16, 0, 0);
    }
    __syncthreads();
#pragma unroll
    for (int kk = 0; kk < 64; kk += 32) {
      bf16x8 af[4], bfr[4];
#pragma unroll
      for (int mi = 0; mi < 4; ++mi)
        af[mi] = *(const bf16x8*)&As[(wm + mi * 16 + li) * 64 + kk + grp * 8];
#pragma unroll
      for (int ni = 0; ni < 4; ++ni)
        bfr[ni] = *(const bf16x8*)&Bs[(wn + ni * 16 + li) * 64 + kk + grp * 8];
#pragma unroll
      for (int mi = 0; mi < 4; ++mi)
#pragma unroll
        for (int ni = 0; ni < 4; ++ni)
          acc[mi][ni] = MFMA16(af[mi], bfr[ni], acc[mi][ni]);
    }
    __syncthreads();
  }
#pragma unroll
  for (int mi = 0; mi < 4; ++mi) {
#pragma unroll
    for (int ni = 0; ni < 4; ++ni) {
      f32x4 v = acc[mi][ni];
      int n = n0 + wn + ni * 16 + li;
#pragma unroll
      for (int r = 0; r < 4; ++r) {
        int m = m0 + wm + mi * 16 + grp * 4 + r;
        if (MODE == 2) {
          ((float*)Cout)[(long)m * N + n] = v[r];
        } else {
          int b = m >> 11, sq = m & 2047;
          int h = n >> 6, dh = n & 63;
          if (MODE == 0)
            ((short*)Cout)[(((long)(b * 16 + h) * 2048 + sq) << 6) + dh] = f2b(v[r] * oscale);
          else
            ((short*)Cout)[(((long)(b * 16 + h) * 64 + dh) << 11) + sq] = f2b(v[r] * oscale);
        }
      }
    }
  }
}

// ---------------------------------------------------------------- attention v3
// Swapped-operand 32x32 MFMA flash attention. Qh (pre-scaled 1/8): [B,H,S,64];
// Kh: [B,H,S,64]; Vt: [B,H,64,S]; Xb out: [B,S,D] bf16.
// Block = 4 waves x 32 q-rows = 128 q. K/V tiles (64 keys) in LDS, dbuf,
// XOR-swizzled (both-sides w/ global_load_lds pre-swizzled source).
__global__ __launch_bounds__(256) void attn_fwd(const short* __restrict__ Qh,
                                                const short* __restrict__ Kh,
                                                const short* __restrict__ Vt,
                                                short* __restrict__ Xb) {
  __shared__ __align__(16) short Ks[2][4096];
  __shared__ __align__(16) short Vs[2][4096];
  const int bh = blockIdx.x;
  const int qt = 15 - (int)blockIdx.y;  // heavy first
  const int t = threadIdx.x, l = t & 63, w = t >> 6;
  const int q = l & 31, hi = l >> 5;
  const int q0w = qt * 128 + w * 32;
  const int qg = q0w + q;
  const short* Qp = Qh + (long)bh * 131072;
  const char* Kb = (const char*)(Kh + (long)bh * 131072);
  const char* Vb = (const char*)(Vt + (long)bh * 131072);

  // Q B-fragments: B[j=q][k=d], k = kd*16 + hi*8 + e
  bf16x8 qf[4];
#pragma unroll
  for (int kd = 0; kd < 4; ++kd)
    qf[kd] = *(const bf16x8*)(Qp + (long)qg * 64 + kd * 16 + hi * 8);

  const int co0 = t * 16, co1 = co0 + 4096;  // each thread stages 2x16B per matrix

  f32x16 oa = {}, ob = {};  // O^T accum: dh 0-31 / 32-63
  float mrun = -1e30f, lsum = 0.f;
  const int myTrips = (q0w >> 6) + 1;
  const int nt = 2 * qt + 2;

#define STAGE(KT, BUF)                                                                   \
  {                                                                                      \
    long ktb = (long)(KT) * 8192;                                                        \
    _Pragma("unroll") for (int c = 0; c < 2; ++c) {                                      \
      int o = c ? co1 : co0;                                                             \
      int ksrc = o ^ (((o >> 7) & 7) << 4);                                              \
      __builtin_amdgcn_global_load_lds(                                                  \
          (const __attribute__((address_space(1))) void*)(Kb + ktb + ksrc),              \
          (__attribute__((address_space(3))) void*)((char*)Ks[BUF] + o), 16, 0, 0);      \
      int row = o >> 7, c16 = (o >> 4) & 7;                                              \
      int vsrc = row * 4096 + (KT) * 128 + (((c16 ^ (row & 7))) << 4);                   \
      __builtin_amdgcn_global_load_lds(                                                  \
          (const __attribute__((address_space(1))) void*)(Vb + vsrc),                    \
          (__attribute__((address_space(3))) void*)((char*)Vs[BUF] + o), 16, 0, 0);      \
    }                                                                                    \
  }

  STAGE(0, 0);
  __syncthreads();

  for (int kt = 0; kt < nt; ++kt) {
    const int buf = kt & 1;
    if (kt + 1 < nt) STAGE(kt + 1, buf ^ 1);

    if (kt < myTrips) {
      const bool diag = (kt == myTrips - 1);
      const int khmax = (diag && ((q0w & 32) == 0)) ? 1 : 2;

      // ---- QK^T swapped: D[key][q], A=K rows, B=Q
      f32x16 p0 = {}, p1 = {};
#pragma unroll
      for (int kd = 0; kd < 4; ++kd) {
        int colB = kd * 32 + hi * 16;
        bf16x8 kf0 = *(const bf16x8*)((const char*)Ks[buf] + q * 128 + (colB ^ ((q & 7) << 4)));
        p0 = MFMA32(kf0, qf[kd], p0);
      }
      if (khmax == 2) {
#pragma unroll
        for (int kd = 0; kd < 4; ++kd) {
          int colB = kd * 32 + hi * 16;
          bf16x8 kf1 = *(const bf16x8*)((const char*)Ks[buf] + (q + 32) * 128 + (colB ^ ((q & 7) << 4)));
          p1 = MFMA32(kf1, qf[kd], p1);
        }
      }
      // ---- causal mask (diag tile only)
      if (diag) {
#pragma unroll
        for (int r = 0; r < 16; ++r) {
          int key0 = kt * 64 + (r & 3) + 8 * (r >> 2) + 4 * hi;
          if (key0 > qg) p0[r] = -1e30f;
          if (key0 + 32 > qg) p1[r] = -1e30f;
        }
      }
      // ---- online softmax (lane-local row)
      float pm = p0[0];
#pragma unroll
      for (int r = 1; r < 16; ++r) pm = fmaxf(pm, p0[r]);
      if (khmax == 2) {
#pragma unroll
        for (int r = 0; r < 16; ++r) pm = fmaxf(pm, p1[r]);
      }
      pm = fmaxf(pm, __shfl_xor(pm, 32));
      float mn = fmaxf(mrun, pm);
      float alpha = __expf(mrun - mn);
      mrun = mn;
      float ts = 0.f;
#pragma unroll
      for (int r = 0; r < 16; ++r) { p0[r] = __expf(p0[r] - mn); ts += p0[r]; }
      if (khmax == 2) {
#pragma unroll
        for (int r = 0; r < 16; ++r) { p1[r] = __expf(p1[r] - mn); ts += p1[r]; }
      }
      ts += __shfl_xor(ts, 32);
      lsum = lsum * alpha + ts;
#pragma unroll
      for (int r = 0; r < 16; ++r) { oa[r] *= alpha; ob[r] *= alpha; }

      // ---- pack P to bf16 + cross-half exchange (T12)
      unsigned own0[8], prt0[8], own1[8], prt1[8];
#pragma unroll
      for (int g = 0; g < 4; ++g) {
        own0[2 * g]     = cvtpk(p0[4 * g], p0[4 * g + 1]);
        own0[2 * g + 1] = cvtpk(p0[4 * g + 2], p0[4 * g + 3]);
      }
#pragma unroll
      for (int i = 0; i < 8; ++i) prt0[i] = __shfl_xor(own0[i], 32);
      if (khmax == 2) {
#pragma unroll
        for (int g = 0; g < 4; ++g) {
          own1[2 * g]     = cvtpk(p1[4 * g], p1[4 * g + 1]);
          own1[2 * g + 1] = cvtpk(p1[4 * g + 2], p1[4 * g + 3]);
        }
#pragma unroll
        for (int i = 0; i < 8; ++i) prt1[i] = __shfl_xor(own1[i], 32);
      }

      // ---- PV: D[d][q] += sum_key V^T[d,key] P[q,key]
#define PVSTEP(KD, OWN, PRT)                                                              \
      {                                                                                   \
        const int kdl = (KD) & 1;                                                         \
        unsigned b0 = hi ? PRT[4 * kdl + 2] : OWN[4 * kdl];                               \
        unsigned b1 = hi ? PRT[4 * kdl + 3] : OWN[4 * kdl + 1];                           \
        unsigned b2 = hi ? OWN[4 * kdl + 2] : PRT[4 * kdl];                               \
        unsigned b3 = hi ? OWN[4 * kdl + 3] : PRT[4 * kdl + 1];                           \
        int4 bi = {(int)b0, (int)b1, (int)b2, (int)b3};                                   \
        bf16x8 pb = __builtin_bit_cast(bf16x8, bi);                                       \
        int colB = (KD) * 32 + hi * 16;                                                   \
        bf16x8 vf0 = *(const bf16x8*)((const char*)Vs[buf] + q * 128 + (colB ^ ((q & 7) << 4)));          \
        bf16x8 vf1 = *(const bf16x8*)((const char*)Vs[buf] + (q + 32) * 128 + (colB ^ ((q & 7) << 4)));   \
        oa = MFMA32(vf0, pb, oa);                                                         \
        ob = MFMA32(vf1, pb, ob);                                                         \
      }
      PVSTEP(0, own0, prt0);
      PVSTEP(1, own0, prt0);
      if (khmax == 2) {
        PVSTEP(2, own1, prt1);
        PVSTEP(3, own1, prt1);
      }
#undef PVSTEP
    }
    __syncthreads();
  }

  // ---- epilogue: O[qg][dh] = O^T/lsum, dh = dhh*32 + 8g + 4hi + (0..3)
  const float inv = 1.f / lsum;
  const int b = bh >> 4, h = bh & 15;
  short* orow = Xb + (long)(b * 2048 + qg) * 1024 + h * 64;
#pragma unroll
  for (int g = 0; g < 4; ++g) {
    {
      unsigned u0 = cvtpk(oa[4 * g] * inv, oa[4 * g + 1] * inv);
      unsigned u1 = cvtpk(oa[4 * g + 2] * inv, oa[4 * g + 3] * inv);
      uint2 uu = {u0, u1};
      *(uint2*)(orow + 8 * g + 4 * hi) = uu;
    }
    {
      unsigned u0 = cvtpk(ob[4 * g] * inv, ob[4 * g + 1] * inv);
      unsigned u1 = cvtpk(ob[4 * g + 2] * inv, ob[4 * g + 3] * inv);
      uint2 uu = {u0, u1};
      *(uint2*)(orow + 32 + 8 * g + 4 * hi) = uu;
    }
  }
}

// ---------------------------------------------------------------- launch
extern "C" void kernel_launch(void* const* d_in, const int* in_sizes, int n_in,
                              void* d_out, int out_size, void* d_ws, size_t ws_size,
                              hipStream_t stream) {
  const float* q  = (const float*)d_in[0];
  const float* k  = (const float*)d_in[1];
  const float* v  = (const float*)d_in[2];
  // d_in[3] = causal tril mask, hardcoded in attn_fwd
  const float* wq = (const float*)d_in[4];
  const float* wk = (const float*)d_in[5];
  const float* wv = (const float*)d_in[6];
  const float* wo = (const float*)d_in[7];

  short* ws = (short*)d_ws;
  const long T = 8388608;  // B*S*D
  short* qb  = ws;
  short* kb  = qb + T;
  short* vb  = kb + T;
  short* Qh  = vb + T;
  short* Kh  = Qh + T;
  short* Vt  = Kh + T;
  short* Xb  = Vt + T;
  short* wqb = Xb + T;
  short* wkb = wqb + 1048576;
  short* wvb = wkb + 1048576;
  short* wob = wvb + 1048576;

  cvt_bf16<<<4096, 256, 0, stream>>>(q, qb, 1048576);
  cvt_bf16<<<4096, 256, 0, stream>>>(k, kb, 1048576);
  cvt_bf16<<<4096, 256, 0, stream>>>(v, vb, 1048576);
  cvt_bf16<<<512, 256, 0, stream>>>(wq, wqb, 131072);
  cvt_bf16<<<512, 256, 0, stream>>>(wk, wkb, 131072);
  cvt_bf16<<<512, 256, 0, stream>>>(wv, wvb, 131072);
  cvt_bf16<<<512, 256, 0, stream>>>(wo, wob, 131072);

  gemm_bt<0><<<512, 256, 0, stream>>>(qb, wqb, (void*)Qh, 8192, 1024, 1024, 0.125f);
  gemm_bt<0><<<512, 256, 0, stream>>>(kb, wkb, (void*)Kh, 8192, 1024, 1024, 1.0f);
  gemm_bt<1><<<512, 256, 0, stream>>>(vb, wvb, (void*)Vt, 8192, 1024, 1024, 1.0f);
  attn_fwd<<<dim3(64, 16), 256, 0, stream>>>(Qh, Kh, Vt, Xb);
  gemm_bt<2><<<512, 256, 0, stream>>>(Xb, wob, d_out, 8192, 1024, 1024, 1.0f);
}

// Round 4
// 223.822 us; speedup vs baseline: 2.7112x; 1.0752x over previous
//
#include <hip/hip_runtime.h>
#include <hip/hip_bf16.h>

typedef __attribute__((ext_vector_type(8))) short bf16x8;
typedef __attribute__((ext_vector_type(4))) float f32x4;
typedef __attribute__((ext_vector_type(16))) float f32x16;

#define MFMA16(a, b, c) __builtin_amdgcn_mfma_f32_16x16x32_bf16((a), (b), (c), 0, 0, 0)
#define MFMA32(a, b, c) __builtin_amdgcn_mfma_f32_32x32x16_bf16((a), (b), (c), 0, 0, 0)

#if defined(__has_builtin)
#if __has_builtin(__builtin_amdgcn_exp2f)
#define EXP2(x) __builtin_amdgcn_exp2f(x)
#endif
#endif
#ifndef EXP2
#define EXP2(x) exp2f(x)
#endif

__device__ __forceinline__ short f2b(float f) {
  unsigned u = __builtin_bit_cast(unsigned, f);
  u += 0x7FFFu + ((u >> 16) & 1u);
  return (short)(u >> 16);
}
__device__ __forceinline__ unsigned cvtpk(float lo, float hi) {
  unsigned r;
  asm("v_cvt_pk_bf16_f32 %0, %1, %2" : "=v"(r) : "v"(lo), "v"(hi));
  return r;
}

// ---------------------------------------------------------------- convert
__global__ __launch_bounds__(256) void cvt_bf16(const float* __restrict__ s,
                                                short* __restrict__ d, int n8) {
  int i = blockIdx.x * 256 + threadIdx.x;
  if (i >= n8) return;
  const float4* sp = (const float4*)s;
  float4 a = sp[2 * i], b = sp[2 * i + 1];
  bf16x8 o;
  o[0] = f2b(a.x); o[1] = f2b(a.y); o[2] = f2b(a.z); o[3] = f2b(a.w);
  o[4] = f2b(b.x); o[5] = f2b(b.y); o[6] = f2b(b.z); o[7] = f2b(b.w);
  *(bf16x8*)(d + (long)i * 8) = o;
}

// ---------------------------------------------------------------- GEMM
template <int MODE>
__global__ __launch_bounds__(256) void gemm_bt(const short* __restrict__ A,
                                               const short* __restrict__ BT,
                                               void* __restrict__ Cout,
                                               int M, int N, int K, float oscale) {
  __shared__ __align__(16) short As[128 * 64];
  __shared__ __align__(16) short Bs[128 * 64];
  const int t = threadIdx.x;
  const int l = t & 63, w = t >> 6;
  const int grp = l >> 4, li = l & 15;
  const int nbn = N >> 7;
  const int bm = (int)blockIdx.x / nbn, bn = (int)blockIdx.x % nbn;
  const int m0 = bm << 7, n0 = bn << 7;
  const int wm = (w >> 1) << 6, wn = (w & 1) << 6;
  const int srow = t >> 3, scol = (t & 7) << 3;
  f32x4 acc[4][4] = {};
  for (int kt = 0; kt < K; kt += 64) {
#pragma unroll
    for (int i = 0; i < 4; ++i) {
      const short* ga = A + (long)(m0 + i * 32 + srow) * K + kt + scol;
      __builtin_amdgcn_global_load_lds(
          (const __attribute__((address_space(1))) void*)ga,
          (__attribute__((address_space(3))) void*)&As[i * 2048 + t * 8], 16, 0, 0);
    }
#pragma unroll
    for (int i = 0; i < 4; ++i) {
      const short* gb = BT + (long)(n0 + i * 32 + srow) * K + kt + scol;
      __builtin_amdgcn_global_load_lds(
          (const __attribute__((address_space(1))) void*)gb,
          (__attribute__((address_space(3))) void*)&Bs[i * 2048 + t * 8], 16, 0, 0);
    }
    __syncthreads();
#pragma unroll
    for (int kk = 0; kk < 64; kk += 32) {
      bf16x8 af[4], bfr[4];
#pragma unroll
      for (int mi = 0; mi < 4; ++mi)
        af[mi] = *(const bf16x8*)&As[(wm + mi * 16 + li) * 64 + kk + grp * 8];
#pragma unroll
      for (int ni = 0; ni < 4; ++ni)
        bfr[ni] = *(const bf16x8*)&Bs[(wn + ni * 16 + li) * 64 + kk + grp * 8];
#pragma unroll
      for (int mi = 0; mi < 4; ++mi)
#pragma unroll
        for (int ni = 0; ni < 4; ++ni)
          acc[mi][ni] = MFMA16(af[mi], bfr[ni], acc[mi][ni]);
    }
    __syncthreads();
  }
#pragma unroll
  for (int mi = 0; mi < 4; ++mi) {
#pragma unroll
    for (int ni = 0; ni < 4; ++ni) {
      f32x4 v = acc[mi][ni];
      int n = n0 + wn + ni * 16 + li;
#pragma unroll
      for (int r = 0; r < 4; ++r) {
        int m = m0 + wm + mi * 16 + grp * 4 + r;
        if (MODE == 2) {
          ((float*)Cout)[(long)m * N + n] = v[r];
        } else {
          int b = m >> 11, sq = m & 2047;
          int h = n >> 6, dh = n & 63;
          if (MODE == 0)
            ((short*)Cout)[(((long)(b * 16 + h) * 2048 + sq) << 6) + dh] = f2b(v[r] * oscale);
          else
            ((short*)Cout)[(((long)(b * 16 + h) * 64 + dh) << 11) + sq] = f2b(v[r] * oscale);
        }
      }
    }
  }
}

// ---------------------------------------------------------------- attention v4
// Balanced-pair swapped-operand 32x32 flash attention, exp2-domain softmax.
// Qh pre-scaled by 0.125*log2(e). Each block: supertile pair (a, 15-a),
// 4 waves x (2x32) q-rows. K/V 64-key tiles in LDS, dbuf, XOR-swizzled.
__device__ __forceinline__ void attn_tile(const short* Kbuf, const short* Vbuf,
                                          const bf16x8 qf[4], f32x16& oa, f32x16& ob,
                                          float& mrun, float& lsum, int kt, bool diag,
                                          int khmax, int qg, int q, int hi) {
  // ---- QK^T swapped: D[key][q], A=K rows, B=Q
  f32x16 p0 = {}, p1 = {};
  __builtin_amdgcn_s_setprio(1);
#pragma unroll
  for (int kd = 0; kd < 4; ++kd) {
    int colB = kd * 32 + hi * 16;
    bf16x8 kf0 = *(const bf16x8*)((const char*)Kbuf + q * 128 + (colB ^ ((q & 7) << 4)));
    p0 = MFMA32(kf0, qf[kd], p0);
  }
  if (khmax == 2) {
#pragma unroll
    for (int kd = 0; kd < 4; ++kd) {
      int colB = kd * 32 + hi * 16;
      bf16x8 kf1 = *(const bf16x8*)((const char*)Kbuf + (q + 32) * 128 + (colB ^ ((q & 7) << 4)));
      p1 = MFMA32(kf1, qf[kd], p1);
    }
  }
  __builtin_amdgcn_s_setprio(0);
  // ---- causal mask (diag tile only)
  if (diag) {
#pragma unroll
    for (int r = 0; r < 16; ++r) {
      int key0 = kt * 64 + (r & 3) + 8 * (r >> 2) + 4 * hi;
      if (key0 > qg) p0[r] = -1e30f;
      if (key0 + 32 > qg) p1[r] = -1e30f;
    }
  }
  // ---- online softmax in log2 domain (lane-local row)
  float pm = p0[0];
#pragma unroll
  for (int r = 1; r < 16; ++r) pm = fmaxf(pm, p0[r]);
  if (khmax == 2) {
#pragma unroll
    for (int r = 0; r < 16; ++r) pm = fmaxf(pm, p1[r]);
  }
  pm = fmaxf(pm, __shfl_xor(pm, 32));
  const bool skip = __all(pm - mrun <= 11.5f);  // T13 defer-max (log2 units)
  float mn;
  float alpha = 1.f;
  if (skip) {
    mn = mrun;
  } else {
    mn = fmaxf(mrun, pm);
    alpha = EXP2(mrun - mn);
    mrun = mn;
  }
  float ts = 0.f;
#pragma unroll
  for (int r = 0; r < 16; ++r) { p0[r] = EXP2(p0[r] - mn); ts += p0[r]; }
  if (khmax == 2) {
#pragma unroll
    for (int r = 0; r < 16; ++r) { p1[r] = EXP2(p1[r] - mn); ts += p1[r]; }
  }
  ts += __shfl_xor(ts, 32);
  if (skip) {
    lsum += ts;
  } else {
    lsum = lsum * alpha + ts;
#pragma unroll
    for (int r = 0; r < 16; ++r) { oa[r] *= alpha; ob[r] *= alpha; }
  }
  // ---- pack P to bf16 + cross-half exchange (T12)
  unsigned own0[8], prt0[8], own1[8], prt1[8];
#pragma unroll
  for (int g = 0; g < 4; ++g) {
    own0[2 * g]     = cvtpk(p0[4 * g], p0[4 * g + 1]);
    own0[2 * g + 1] = cvtpk(p0[4 * g + 2], p0[4 * g + 3]);
  }
#pragma unroll
  for (int i = 0; i < 8; ++i) prt0[i] = __shfl_xor(own0[i], 32);
  if (khmax == 2) {
#pragma unroll
    for (int g = 0; g < 4; ++g) {
      own1[2 * g]     = cvtpk(p1[4 * g], p1[4 * g + 1]);
      own1[2 * g + 1] = cvtpk(p1[4 * g + 2], p1[4 * g + 3]);
    }
#pragma unroll
    for (int i = 0; i < 8; ++i) prt1[i] = __shfl_xor(own1[i], 32);
  }
  // ---- PV: D[d][q] += sum_key V^T[d,key] P[q,key]
  __builtin_amdgcn_s_setprio(1);
#define PVSTEP(KD, OWN, PRT)                                                              \
  {                                                                                       \
    const int kdl = (KD) & 1;                                                             \
    unsigned b0 = hi ? PRT[4 * kdl + 2] : OWN[4 * kdl];                                   \
    unsigned b1 = hi ? PRT[4 * kdl + 3] : OWN[4 * kdl + 1];                               \
    unsigned b2 = hi ? OWN[4 * kdl + 2] : PRT[4 * kdl];                                   \
    unsigned b3 = hi ? OWN[4 * kdl + 3] : PRT[4 * kdl + 1];                               \
    int4 bi = {(int)b0, (int)b1, (int)b2, (int)b3};                                       \
    bf16x8 pb = __builtin_bit_cast(bf16x8, bi);                                           \
    int colB = (KD) * 32 + hi * 16;                                                       \
    bf16x8 vf0 = *(const bf16x8*)((const char*)Vbuf + q * 128 + (colB ^ ((q & 7) << 4))); \
    bf16x8 vf1 = *(const bf16x8*)((const char*)Vbuf + (q + 32) * 128 + (colB ^ ((q & 7) << 4))); \
    oa = MFMA32(vf0, pb, oa);                                                             \
    ob = MFMA32(vf1, pb, ob);                                                             \
  }
  PVSTEP(0, own0, prt0);
  PVSTEP(1, own0, prt0);
  if (khmax == 2) {
    PVSTEP(2, own1, prt1);
    PVSTEP(3, own1, prt1);
  }
#undef PVSTEP
  __builtin_amdgcn_s_setprio(0);
}

__global__ __launch_bounds__(256, 2) void attn_fwd(const short* __restrict__ Qh,
                                                   const short* __restrict__ Kh,
                                                   const short* __restrict__ Vt,
                                                   short* __restrict__ Xb) {
  __shared__ __align__(16) short Ks[2][4096];
  __shared__ __align__(16) short Vs[2][4096];
  const int bh = blockIdx.x;
  const int qtA = blockIdx.y;        // 0..7 (light)
  const int qtB = 15 - qtA;          // heavy partner
  const int t = threadIdx.x, l = t & 63, w = t >> 6;
  const int q = l & 31, hi = l >> 5;
  const int q0wA = qtA * 128 + w * 32, q0wB = qtB * 128 + w * 32;
  const int qgA = q0wA + q, qgB = q0wB + q;
  const short* Qp = Qh + (long)bh * 131072;
  const char* Kb = (const char*)(Kh + (long)bh * 131072);
  const char* Vb = (const char*)(Vt + (long)bh * 131072);

  bf16x8 qfA[4], qfB[4];
#pragma unroll
  for (int kd = 0; kd < 4; ++kd) {
    qfA[kd] = *(const bf16x8*)(Qp + (long)qgA * 64 + kd * 16 + hi * 8);
    qfB[kd] = *(const bf16x8*)(Qp + (long)qgB * 64 + kd * 16 + hi * 8);
  }

  const int co0 = t * 16, co1 = co0 + 4096;

  f32x16 oaA = {}, obA = {}, oaB = {}, obB = {};
  float mrunA = -1e30f, lsumA = 0.f, mrunB = -1e30f, lsumB = 0.f;
  const int tripsA = (q0wA >> 6) + 1;
  const int tripsB = (q0wB >> 6) + 1;
  const int nt = 2 * qtB + 2;

#define STAGE(KT, BUF)                                                                   \
  {                                                                                      \
    long ktb = (long)(KT) * 8192;                                                        \
    _Pragma("unroll") for (int c = 0; c < 2; ++c) {                                      \
      int o = c ? co1 : co0;                                                             \
      int ksrc = o ^ (((o >> 7) & 7) << 4);                                              \
      __builtin_amdgcn_global_load_lds(                                                  \
          (const __attribute__((address_space(1))) void*)(Kb + ktb + ksrc),              \
          (__attribute__((address_space(3))) void*)((char*)Ks[BUF] + o), 16, 0, 0);      \
      int row = o >> 7, c16 = (o >> 4) & 7;                                              \
      int vsrc = row * 4096 + (KT) * 128 + (((c16 ^ (row & 7))) << 4);                   \
      __builtin_amdgcn_global_load_lds(                                                  \
          (const __attribute__((address_space(1))) void*)(Vb + vsrc),                    \
          (__attribute__((address_space(3))) void*)((char*)Vs[BUF] + o), 16, 0, 0);      \
    }                                                                                    \
  }

  STAGE(0, 0);
  __syncthreads();

  for (int kt = 0; kt < nt; ++kt) {
    const int buf = kt & 1;
    if (kt + 1 < nt) STAGE(kt + 1, buf ^ 1);

    if (kt < tripsB) {
      const bool diag = (kt == tripsB - 1);
      const int khmax = (diag && ((q0wB & 32) == 0)) ? 1 : 2;
      attn_tile(Ks[buf], Vs[buf], qfB, oaB, obB, mrunB, lsumB, kt, diag, khmax, qgB, q, hi);
    }
    if (kt < tripsA) {
      const bool diag = (kt == tripsA - 1);
      const int khmax = (diag && ((q0wA & 32) == 0)) ? 1 : 2;
      attn_tile(Ks[buf], Vs[buf], qfA, oaA, obA, mrunA, lsumA, kt, diag, khmax, qgA, q, hi);
    }
    __syncthreads();
  }

  const int b = bh >> 4, h = bh & 15;
#define EPI(OA, OB, LS, QG)                                                \
  {                                                                        \
    const float inv = 1.f / (LS);                                          \
    short* orow = Xb + (long)(b * 2048 + (QG)) * 1024 + h * 64;            \
    _Pragma("unroll") for (int g = 0; g < 4; ++g) {                        \
      unsigned u0 = cvtpk((OA)[4 * g] * inv, (OA)[4 * g + 1] * inv);       \
      unsigned u1 = cvtpk((OA)[4 * g + 2] * inv, (OA)[4 * g + 3] * inv);   \
      uint2 uu = {u0, u1};                                                 \
      *(uint2*)(orow + 8 * g + 4 * hi) = uu;                               \
      unsigned w0 = cvtpk((OB)[4 * g] * inv, (OB)[4 * g + 1] * inv);       \
      unsigned w1 = cvtpk((OB)[4 * g + 2] * inv, (OB)[4 * g + 3] * inv);   \
      uint2 ww = {w0, w1};                                                 \
      *(uint2*)(orow + 32 + 8 * g + 4 * hi) = ww;                          \
    }                                                                      \
  }
  EPI(oaA, obA, lsumA, qgA);
  EPI(oaB, obB, lsumB, qgB);
#undef EPI
}

// ---------------------------------------------------------------- launch
extern "C" void kernel_launch(void* const* d_in, const int* in_sizes, int n_in,
                              void* d_out, int out_size, void* d_ws, size_t ws_size,
                              hipStream_t stream) {
  const float* q  = (const float*)d_in[0];
  const float* k  = (const float*)d_in[1];
  const float* v  = (const float*)d_in[2];
  // d_in[3] = causal tril mask, hardcoded in attn_fwd
  const float* wq = (const float*)d_in[4];
  const float* wk = (const float*)d_in[5];
  const float* wv = (const float*)d_in[6];
  const float* wo = (const float*)d_in[7];

  short* ws = (short*)d_ws;
  const long T = 8388608;  // B*S*D
  short* qb  = ws;
  short* kb  = qb + T;
  short* vb  = kb + T;
  short* Qh  = vb + T;
  short* Kh  = Qh + T;
  short* Vt  = Kh + T;
  short* Xb  = Vt + T;
  short* wqb = Xb + T;
  short* wkb = wqb + 1048576;
  short* wvb = wkb + 1048576;
  short* wob = wvb + 1048576;

  cvt_bf16<<<4096, 256, 0, stream>>>(q, qb, 1048576);
  cvt_bf16<<<4096, 256, 0, stream>>>(k, kb, 1048576);
  cvt_bf16<<<4096, 256, 0, stream>>>(v, vb, 1048576);
  cvt_bf16<<<512, 256, 0, stream>>>(wq, wqb, 131072);
  cvt_bf16<<<512, 256, 0, stream>>>(wk, wkb, 131072);
  cvt_bf16<<<512, 256, 0, stream>>>(wv, wvb, 131072);
  cvt_bf16<<<512, 256, 0, stream>>>(wo, wob, 131072);

  // Q pre-scaled by 0.125 * log2(e) for exp2-domain softmax
  gemm_bt<0><<<512, 256, 0, stream>>>(qb, wqb, (void*)Qh, 8192, 1024, 1024, 0.18033688f);
  gemm_bt<0><<<512, 256, 0, stream>>>(kb, wkb, (void*)Kh, 8192, 1024, 1024, 1.0f);
  gemm_bt<1><<<512, 256, 0, stream>>>(vb, wvb, (void*)Vt, 8192, 1024, 1024, 1.0f);
  attn_fwd<<<dim3(64, 8), 256, 0, stream>>>(Qh, Kh, Vt, Xb);
  gemm_bt<2><<<512, 256, 0, stream>>>(Xb, wob, d_out, 8192, 1024, 1024, 1.0f);
}

// Round 6
// 216.063 us; speedup vs baseline: 2.8085x; 1.0359x over previous
//
#include <hip/hip_runtime.h>
#include <hip/hip_bf16.h>

typedef __attribute__((ext_vector_type(8))) short bf16x8;
typedef __attribute__((ext_vector_type(4))) float f32x4;
typedef __attribute__((ext_vector_type(16))) float f32x16;

#define MFMA16(a, b, c) __builtin_amdgcn_mfma_f32_16x16x32_bf16((a), (b), (c), 0, 0, 0)
#define MFMA32(a, b, c) __builtin_amdgcn_mfma_f32_32x32x16_bf16((a), (b), (c), 0, 0, 0)

#if defined(__has_builtin)
#if __has_builtin(__builtin_amdgcn_exp2f)
#define EXP2(x) __builtin_amdgcn_exp2f(x)
#endif
#endif
#ifndef EXP2
#define EXP2(x) exp2f(x)
#endif

__device__ __forceinline__ short f2b(float f) {
  unsigned u = __builtin_bit_cast(unsigned, f);
  u += 0x7FFFu + ((u >> 16) & 1u);
  return (short)(u >> 16);
}
__device__ __forceinline__ unsigned cvtpk(float lo, float hi) {
  unsigned r;
  asm("v_cvt_pk_bf16_f32 %0, %1, %2" : "=v"(r) : "v"(lo), "v"(hi));
  return r;
}

// ---------------------------------------------------------------- converts
__global__ __launch_bounds__(256) void cvt3_bf16(const float* __restrict__ s0,
                                                 const float* __restrict__ s1,
                                                 const float* __restrict__ s2,
                                                 short* __restrict__ d, long stride) {
  const int which = blockIdx.y;
  const float* s = which == 0 ? s0 : (which == 1 ? s1 : s2);
  long i = (long)blockIdx.x * 256 + threadIdx.x;
  const float4* sp = (const float4*)s;
  float4 a = sp[2 * i], b = sp[2 * i + 1];
  bf16x8 o;
  o[0] = f2b(a.x); o[1] = f2b(a.y); o[2] = f2b(a.z); o[3] = f2b(a.w);
  o[4] = f2b(b.x); o[5] = f2b(b.y); o[6] = f2b(b.z); o[7] = f2b(b.w);
  *(bf16x8*)(d + which * stride + i * 8) = o;
}
__global__ __launch_bounds__(256) void cvt4_bf16(const float* __restrict__ s0,
                                                 const float* __restrict__ s1,
                                                 const float* __restrict__ s2,
                                                 const float* __restrict__ s3,
                                                 short* __restrict__ d, long stride) {
  const int which = blockIdx.y;
  const float* s = which == 0 ? s0 : (which == 1 ? s1 : (which == 2 ? s2 : s3));
  long i = (long)blockIdx.x * 256 + threadIdx.x;
  const float4* sp = (const float4*)s;
  float4 a = sp[2 * i], b = sp[2 * i + 1];
  bf16x8 o;
  o[0] = f2b(a.x); o[1] = f2b(a.y); o[2] = f2b(a.z); o[3] = f2b(a.w);
  o[4] = f2b(b.x); o[5] = f2b(b.y); o[6] = f2b(b.z); o[7] = f2b(b.w);
  *(bf16x8*)(d + which * stride + i * 8) = o;
}

// ---------------------------------------------------------------- GEMM (2-phase dbuf)
template <int MODE>
__global__ __launch_bounds__(256) void gemm_bt(const short* __restrict__ A,
                                               const short* __restrict__ BT,
                                               void* __restrict__ Cout,
                                               int M, int N, int K, float oscale) {
  __shared__ __align__(16) short As[2][128 * 64];
  __shared__ __align__(16) short Bs[2][128 * 64];
  const int t = threadIdx.x;
  const int l = t & 63, w = t >> 6;
  const int grp = l >> 4, li = l & 15;
  const int nbn = N >> 7;
  const int bm = (int)blockIdx.x / nbn, bn = (int)blockIdx.x % nbn;
  const int m0 = bm << 7, n0 = bn << 7;
  const int wm = (w >> 1) << 6, wn = (w & 1) << 6;
  const int srow = t >> 3, scol = (t & 7) << 3;
  const int NT = K >> 6;
  f32x4 acc[4][4] = {};

#define GSTAGE(KT, BUF)                                                                    \
  {                                                                                        \
    _Pragma("unroll") for (int i = 0; i < 4; ++i) {                                        \
      const short* ga = A + (long)(m0 + i * 32 + srow) * K + (KT) * 64 + scol;             \
      __builtin_amdgcn_global_load_lds(                                                    \
          (const __attribute__((address_space(1))) void*)ga,                               \
          (__attribute__((address_space(3))) void*)&As[BUF][i * 2048 + t * 8], 16, 0, 0);  \
    }                                                                                      \
    _Pragma("unroll") for (int i = 0; i < 4; ++i) {                                        \
      const short* gb = BT + (long)(n0 + i * 32 + srow) * K + (KT) * 64 + scol;            \
      __builtin_amdgcn_global_load_lds(                                                    \
          (const __attribute__((address_space(1))) void*)gb,                               \
          (__attribute__((address_space(3))) void*)&Bs[BUF][i * 2048 + t * 8], 16, 0, 0);  \
    }                                                                                      \
  }

  GSTAGE(0, 0);
  __syncthreads();
  for (int kt = 0; kt < NT; ++kt) {
    const int cur = kt & 1;
    if (kt + 1 < NT) GSTAGE(kt + 1, cur ^ 1);
#pragma unroll
    for (int kk = 0; kk < 64; kk += 32) {
      bf16x8 af[4], bfr[4];
#pragma unroll
      for (int mi = 0; mi < 4; ++mi)
        af[mi] = *(const bf16x8*)&As[cur][(wm + mi * 16 + li) * 64 + kk + grp * 8];
#pragma unroll
      for (int ni = 0; ni < 4; ++ni)
        bfr[ni] = *(const bf16x8*)&Bs[cur][(wn + ni * 16 + li) * 64 + kk + grp * 8];
#pragma unroll
      for (int mi = 0; mi < 4; ++mi)
#pragma unroll
        for (int ni = 0; ni < 4; ++ni)
          acc[mi][ni] = MFMA16(af[mi], bfr[ni], acc[mi][ni]);
    }
    __syncthreads();
  }
#undef GSTAGE
#pragma unroll
  for (int mi = 0; mi < 4; ++mi) {
#pragma unroll
    for (int ni = 0; ni < 4; ++ni) {
      f32x4 v = acc[mi][ni];
      int n = n0 + wn + ni * 16 + li;
#pragma unroll
      for (int r = 0; r < 4; ++r) {
        int m = m0 + wm + mi * 16 + grp * 4 + r;
        if (MODE == 2) {
          ((float*)Cout)[(long)m * N + n] = v[r];
        } else {
          int b = m >> 11, sq = m & 2047;
          int h = n >> 6, dh = n & 63;
          if (MODE == 0)
            ((short*)Cout)[(((long)(b * 16 + h) * 2048 + sq) << 6) + dh] = f2b(v[r] * oscale);
          else
            ((short*)Cout)[(((long)(b * 16 + h) * 64 + dh) << 11) + sq] = f2b(v[r] * oscale);
        }
      }
    }
  }
}

// ---------------------------------------------------------------- attention v6
// = v4 structure (proven): balanced pairs, swapped 32x32 MFMA, exp2 softmax,
// defer-max, shfl_xor cross-half exchange. (permlane asm reverted: unverified
// instruction orientation broke R5.)
__device__ __forceinline__ void attn_tile(const short* Kbuf, const short* Vbuf,
                                          const bf16x8 qf[4], f32x16& oa, f32x16& ob,
                                          float& mrun, float& lsum, int kt, bool diag,
                                          int khmax, int qg, int q, int hi) {
  // ---- QK^T swapped: D[key][q], A=K rows, B=Q
  f32x16 p0 = {}, p1 = {};
  __builtin_amdgcn_s_setprio(1);
#pragma unroll
  for (int kd = 0; kd < 4; ++kd) {
    int colB = kd * 32 + hi * 16;
    bf16x8 kf0 = *(const bf16x8*)((const char*)Kbuf + q * 128 + (colB ^ ((q & 7) << 4)));
    p0 = MFMA32(kf0, qf[kd], p0);
  }
  if (khmax == 2) {
#pragma unroll
    for (int kd = 0; kd < 4; ++kd) {
      int colB = kd * 32 + hi * 16;
      bf16x8 kf1 = *(const bf16x8*)((const char*)Kbuf + (q + 32) * 128 + (colB ^ ((q & 7) << 4)));
      p1 = MFMA32(kf1, qf[kd], p1);
    }
  }
  __builtin_amdgcn_s_setprio(0);
  // ---- causal mask (diag tile only)
  if (diag) {
#pragma unroll
    for (int r = 0; r < 16; ++r) {
      int key0 = kt * 64 + (r & 3) + 8 * (r >> 2) + 4 * hi;
      if (key0 > qg) p0[r] = -1e30f;
      if (key0 + 32 > qg) p1[r] = -1e30f;
    }
  }
  // ---- online softmax in log2 domain (lane-local row)
  float pm = p0[0];
#pragma unroll
  for (int r = 1; r < 16; ++r) pm = fmaxf(pm, p0[r]);
  if (khmax == 2) {
#pragma unroll
    for (int r = 0; r < 16; ++r) pm = fmaxf(pm, p1[r]);
  }
  pm = fmaxf(pm, __shfl_xor(pm, 32));
  const bool skip = __all(pm - mrun <= 11.5f);  // T13 defer-max (log2 units)
  float mn;
  float alpha = 1.f;
  if (skip) {
    mn = mrun;
  } else {
    mn = fmaxf(mrun, pm);
    alpha = EXP2(mrun - mn);
    mrun = mn;
  }
  float ts = 0.f;
#pragma unroll
  for (int r = 0; r < 16; ++r) { p0[r] = EXP2(p0[r] - mn); ts += p0[r]; }
  if (khmax == 2) {
#pragma unroll
    for (int r = 0; r < 16; ++r) { p1[r] = EXP2(p1[r] - mn); ts += p1[r]; }
  }
  ts += __shfl_xor(ts, 32);
  if (skip) {
    lsum += ts;
  } else {
    lsum = lsum * alpha + ts;
#pragma unroll
    for (int r = 0; r < 16; ++r) { oa[r] *= alpha; ob[r] *= alpha; }
  }
  // ---- pack P to bf16 + cross-half exchange (proven shfl_xor form)
  unsigned own0[8], prt0[8], own1[8], prt1[8];
#pragma unroll
  for (int g = 0; g < 4; ++g) {
    own0[2 * g]     = cvtpk(p0[4 * g], p0[4 * g + 1]);
    own0[2 * g + 1] = cvtpk(p0[4 * g + 2], p0[4 * g + 3]);
  }
#pragma unroll
  for (int i = 0; i < 8; ++i) prt0[i] = __shfl_xor(own0[i], 32);
  if (khmax == 2) {
#pragma unroll
    for (int g = 0; g < 4; ++g) {
      own1[2 * g]     = cvtpk(p1[4 * g], p1[4 * g + 1]);
      own1[2 * g + 1] = cvtpk(p1[4 * g + 2], p1[4 * g + 3]);
    }
#pragma unroll
    for (int i = 0; i < 8; ++i) prt1[i] = __shfl_xor(own1[i], 32);
  }
  // ---- PV: D[d][q] += sum_key V^T[d,key] P[q,key]
  __builtin_amdgcn_s_setprio(1);
#define PVSTEP(KD, OWN, PRT)                                                              \
  {                                                                                       \
    const int kdl = (KD) & 1;                                                             \
    unsigned b0 = hi ? PRT[4 * kdl + 2] : OWN[4 * kdl];                                   \
    unsigned b1 = hi ? PRT[4 * kdl + 3] : OWN[4 * kdl + 1];                               \
    unsigned b2 = hi ? OWN[4 * kdl + 2] : PRT[4 * kdl];                                   \
    unsigned b3 = hi ? OWN[4 * kdl + 3] : PRT[4 * kdl + 1];                               \
    int4 bi = {(int)b0, (int)b1, (int)b2, (int)b3};                                       \
    bf16x8 pb = __builtin_bit_cast(bf16x8, bi);                                           \
    int colB = (KD) * 32 + hi * 16;                                                       \
    bf16x8 vf0 = *(const bf16x8*)((const char*)Vbuf + q * 128 + (colB ^ ((q & 7) << 4))); \
    bf16x8 vf1 = *(const bf16x8*)((const char*)Vbuf + (q + 32) * 128 + (colB ^ ((q & 7) << 4))); \
    oa = MFMA32(vf0, pb, oa);                                                             \
    ob = MFMA32(vf1, pb, ob);                                                             \
  }
  PVSTEP(0, own0, prt0);
  PVSTEP(1, own0, prt0);
  if (khmax == 2) {
    PVSTEP(2, own1, prt1);
    PVSTEP(3, own1, prt1);
  }
#undef PVSTEP
  __builtin_amdgcn_s_setprio(0);
}

__global__ __launch_bounds__(256, 2) void attn_fwd(const short* __restrict__ Qh,
                                                   const short* __restrict__ Kh,
                                                   const short* __restrict__ Vt,
                                                   short* __restrict__ Xb) {
  __shared__ __align__(16) short Ks[2][4096];
  __shared__ __align__(16) short Vs[2][4096];
  const int bh = blockIdx.x;
  const int qtA = blockIdx.y;        // 0..7 (light)
  const int qtB = 15 - qtA;          // heavy partner
  const int t = threadIdx.x, l = t & 63, w = t >> 6;
  const int q = l & 31, hi = l >> 5;
  const int q0wA = qtA * 128 + w * 32, q0wB = qtB * 128 + w * 32;
  const int qgA = q0wA + q, qgB = q0wB + q;
  const short* Qp = Qh + (long)bh * 131072;
  const char* Kb = (const char*)(Kh + (long)bh * 131072);
  const char* Vb = (const char*)(Vt + (long)bh * 131072);

  bf16x8 qfA[4], qfB[4];
#pragma unroll
  for (int kd = 0; kd < 4; ++kd) {
    qfA[kd] = *(const bf16x8*)(Qp + (long)qgA * 64 + kd * 16 + hi * 8);
    qfB[kd] = *(const bf16x8*)(Qp + (long)qgB * 64 + kd * 16 + hi * 8);
  }

  const int co0 = t * 16, co1 = co0 + 4096;

  f32x16 oaA = {}, obA = {}, oaB = {}, obB = {};
  float mrunA = -1e30f, lsumA = 0.f, mrunB = -1e30f, lsumB = 0.f;
  const int tripsA = (q0wA >> 6) + 1;
  const int tripsB = (q0wB >> 6) + 1;
  const int nt = 2 * qtB + 2;

#define STAGE(KT, BUF)                                                                   \
  {                                                                                      \
    long ktb = (long)(KT) * 8192;                                                        \
    _Pragma("unroll") for (int c = 0; c < 2; ++c) {                                      \
      int o = c ? co1 : co0;                                                             \
      int ksrc = o ^ (((o >> 7) & 7) << 4);                                              \
      __builtin_amdgcn_global_load_lds(                                                  \
          (const __attribute__((address_space(1))) void*)(Kb + ktb + ksrc),              \
          (__attribute__((address_space(3))) void*)((char*)Ks[BUF] + o), 16, 0, 0);      \
      int row = o >> 7, c16 = (o >> 4) & 7;                                              \
      int vsrc = row * 4096 + (KT) * 128 + (((c16 ^ (row & 7))) << 4);                   \
      __builtin_amdgcn_global_load_lds(                                                  \
          (const __attribute__((address_space(1))) void*)(Vb + vsrc),                    \
          (__attribute__((address_space(3))) void*)((char*)Vs[BUF] + o), 16, 0, 0);      \
    }                                                                                    \
  }

  STAGE(0, 0);
  __syncthreads();

  for (int kt = 0; kt < nt; ++kt) {
    const int buf = kt & 1;
    if (kt + 1 < nt) STAGE(kt + 1, buf ^ 1);

    if (kt < tripsB) {
      const bool diag = (kt == tripsB - 1);
      const int khmax = (diag && ((q0wB & 32) == 0)) ? 1 : 2;
      attn_tile(Ks[buf], Vs[buf], qfB, oaB, obB, mrunB, lsumB, kt, diag, khmax, qgB, q, hi);
    }
    if (kt < tripsA) {
      const bool diag = (kt == tripsA - 1);
      const int khmax = (diag && ((q0wA & 32) == 0)) ? 1 : 2;
      attn_tile(Ks[buf], Vs[buf], qfA, oaA, obA, mrunA, lsumA, kt, diag, khmax, qgA, q, hi);
    }
    __syncthreads();
  }

  const int b = bh >> 4, h = bh & 15;
#define EPI(OA, OB, LS, QG)                                                \
  {                                                                        \
    const float inv = 1.f / (LS);                                          \
    short* orow = Xb + (long)(b * 2048 + (QG)) * 1024 + h * 64;            \
    _Pragma("unroll") for (int g = 0; g < 4; ++g) {                        \
      unsigned u0 = cvtpk((OA)[4 * g] * inv, (OA)[4 * g + 1] * inv);       \
      unsigned u1 = cvtpk((OA)[4 * g + 2] * inv, (OA)[4 * g + 3] * inv);   \
      uint2 uu = {u0, u1};                                                 \
      *(uint2*)(orow + 8 * g + 4 * hi) = uu;                               \
      unsigned w0 = cvtpk((OB)[4 * g] * inv, (OB)[4 * g + 1] * inv);       \
      unsigned w1 = cvtpk((OB)[4 * g + 2] * inv, (OB)[4 * g + 3] * inv);   \
      uint2 ww = {w0, w1};                                                 \
      *(uint2*)(orow + 32 + 8 * g + 4 * hi) = ww;                          \
    }                                                                      \
  }
  EPI(oaA, obA, lsumA, qgA);
  EPI(oaB, obB, lsumB, qgB);
#undef EPI
}

// ---------------------------------------------------------------- launch
extern "C" void kernel_launch(void* const* d_in, const int* in_sizes, int n_in,
                              void* d_out, int out_size, void* d_ws, size_t ws_size,
                              hipStream_t stream) {
  const float* q  = (const float*)d_in[0];
  const float* k  = (const float*)d_in[1];
  const float* v  = (const float*)d_in[2];
  // d_in[3] = causal tril mask, hardcoded in attn_fwd
  const float* wq = (const float*)d_in[4];
  const float* wk = (const float*)d_in[5];
  const float* wv = (const float*)d_in[6];
  const float* wo = (const float*)d_in[7];

  short* ws = (short*)d_ws;
  const long T = 8388608;  // B*S*D
  short* qb  = ws;
  short* kb  = qb + T;
  short* vb  = kb + T;
  short* Qh  = vb + T;
  short* Kh  = Qh + T;
  short* Vt  = Kh + T;
  short* Xb  = Vt + T;
  short* wqb = Xb + T;
  short* wkb = wqb + 1048576;
  short* wvb = wkb + 1048576;
  short* wob = wvb + 1048576;

  cvt3_bf16<<<dim3(4096, 3), 256, 0, stream>>>(q, k, v, qb, T);
  cvt4_bf16<<<dim3(512, 4), 256, 0, stream>>>(wq, wk, wv, wo, wqb, 1048576);

  // Q pre-scaled by 0.125 * log2(e) for exp2-domain softmax
  gemm_bt<0><<<512, 256, 0, stream>>>(qb, wqb, (void*)Qh, 8192, 1024, 1024, 0.18033688f);
  gemm_bt<0><<<512, 256, 0, stream>>>(kb, wkb, (void*)Kh, 8192, 1024, 1024, 1.0f);
  gemm_bt<1><<<512, 256, 0, stream>>>(vb, wvb, (void*)Vt, 8192, 1024, 1024, 1.0f);
  attn_fwd<<<dim3(64, 8), 256, 0, stream>>>(Qh, Kh, Vt, Xb);
  gemm_bt<2><<<512, 256, 0, stream>>>(Xb, wob, d_out, 8192, 1024, 1024, 1.0f);
}